// Round 16
// baseline (85.679 us; speedup 1.0000x reference)
//
#include <hip/hip_runtime.h>
#include <hip/hip_bf16.h>
#include <stdint.h>

typedef __bf16 bf16_t;
typedef __bf16 bf16x4 __attribute__((ext_vector_type(4)));
typedef __bf16 bf16x8 __attribute__((ext_vector_type(8)));
typedef float  f32x4  __attribute__((ext_vector_type(4)));

#define WAITVM(N) asm volatile("s_waitcnt vmcnt(" #N ")" ::: "memory")

// ---- workspace layout (bytes) ----
static constexpr size_t WT_OFF = 0;                    // Wt bf16 [384][1024] = 768 KB
static constexpr size_t Q_OFF  = (size_t)1 << 20;      // q bf16 (pre-scaled 1/32) 4 MB
static constexpr size_t K_OFF  = Q_OFF + ((size_t)4 << 20);
static constexpr size_t VT_OFF = K_OFF + ((size_t)4 << 20);  // vT bf16 [8][128][2048] = 4 MB

__device__ __forceinline__ void g2lds16(const void* g, void* l) {
  __builtin_amdgcn_global_load_lds(
      (__attribute__((address_space(1))) void*)(g),
      (__attribute__((address_space(3))) void*)(l), 16, 0, 0);
}

// ---------------- W transpose: W[1024][128] fp32 -> Wt[384][1024] bf16 ----------------
__global__ __launch_bounds__(256) void wt_kernel(const float* __restrict__ Wq,
                                                 const float* __restrict__ Wk,
                                                 const float* __restrict__ Wv,
                                                 bf16_t* __restrict__ wt) {
  __shared__ float tile[64][129];
  int wi = blockIdx.x >> 4;
  int ct = blockIdx.x & 15;
  const float* W = (wi == 0) ? Wq : ((wi == 1) ? Wk : Wv);
  int c0 = ct * 64;
  int tid = threadIdx.x;
  for (int i = 0; i < 32; ++i) {
    int idx = i * 256 + tid;
    int c = idx >> 7, n = idx & 127;
    tile[c][n] = W[(size_t)(c0 + c) * 128 + n];
  }
  __syncthreads();
  for (int i = 0; i < 32; ++i) {
    int idx = i * 256 + tid;
    int n = idx >> 6, c = idx & 63;
    wt[(size_t)(wi * 128 + n) * 1024 + c0 + c] = (bf16_t)tile[c][n];
  }
}

// ---------------- fused QKV projection v12: per-wave self-paced (attn pattern) ------
// Grid 768 = 3 slices(n128) x 256 t-tiles(64), XCD-chunked. Block 256 = 4 INDEPENDENT
// waves: (kh = K-half, nh = n-half). Each wave: private dbuf x tile (t64 x k32 fp32,
// 2x8KB g2lds), 16 BK=32 steps over its K-half; wf (4 bf16x8) direct from L2, ping-pong;
// per-wave counted vmcnt, NO barriers in loop. Final: K-half pairs merge via LDS
// (waves 2,3 dump 16KB acc; waves 0,1 add + epilogue). LDS 64KB -> 2 blocks/CU.
__global__ __launch_bounds__(256) void proj_kernel(const float* __restrict__ x,
                                                   const bf16_t* __restrict__ wt,
                                                   bf16_t* __restrict__ q,
                                                   bf16_t* __restrict__ k,
                                                   bf16_t* __restrict__ vT) {
  __shared__ __align__(16) char lds[65536];  // w*16K: x dbuf 2x8K (merge: acc dump)

  int wgid = (blockIdx.x & 7) * 96 + (blockIdx.x >> 3);
  int t_tile = wgid / 3;
  int slice = wgid % 3;          // 0=Q, 1=K, 2=V
  int n0 = slice * 128;
  int t0 = t_tile * 64;

  int tid = threadIdx.x;
  int lane = tid & 63;
  int w = tid >> 6;              // wave: kh = w>>1 (K-half), nh = w&1 (n-half)
  int kh = w >> 1, nh = w & 1;
  int lq = lane & 15, grp = lane >> 4;
  int kb0 = kh * 512;            // this wave's K base (floats)

  const char* xb = (const char*)x;   // row stride 4096 B

  f32x4 acc[4][4];               // [a: n16][sub: t16]
#pragma unroll
  for (int a = 0; a < 4; ++a)
#pragma unroll
    for (int s = 0; s < 4; ++s) acc[a][s] = (f32x4){0.f, 0.f, 0.f, 0.f};

  const bf16_t* wbase = wt + (size_t)(n0 + nh * 64 + lq) * 1024 + kb0 + grp * 8;

  // private x tile [64 t][32 k] fp32 = 8KB, dbuf; swizzle 16B-chunk c^(row&7)
  auto stageX = [&](int slot, int kf0) {   // kf0: float offset within row
#pragma unroll
    for (int j = 0; j < 8; ++j) {
      int off = j * 1024 + lane * 16;
      int row = off >> 7;                  // 0..63 (128B rows)
      int c = (off >> 4) & 7;
      const char* src = xb + (size_t)(t0 + row) * 4096 + (size_t)kf0 * 4
                        + ((c ^ (row & 7)) << 4);
      g2lds16(src, &lds[w * 16384 + slot * 8192 + off]);
    }
  };

#define LOADW(DST, KO)                                                        \
  do {                                                                        \
    DST[0] = *(const bf16x8*)(wbase + 0 * 16384 + (KO));                      \
    DST[1] = *(const bf16x8*)(wbase + 1 * 16384 + (KO));                      \
    DST[2] = *(const bf16x8*)(wbase + 2 * 16384 + (KO));                      \
    DST[3] = *(const bf16x8*)(wbase + 3 * 16384 + (KO));                      \
  } while (0)

  // read xf frags from private buf[slot] (8 ds_read_b128 + cvt -> 4 bf16x8)
#define READX(XF, SLOT)                                                       \
  do {                                                                        \
    _Pragma("unroll") for (int sub = 0; sub < 4; ++sub) {                     \
      int row = sub * 16 + lq;                                                \
      int base = w * 16384 + (SLOT) * 8192 + (row << 7);                      \
      float4 f0 = *(const float4*)(&lds[base + (((grp * 2)     ^ (row & 7)) << 4)]); \
      float4 f1 = *(const float4*)(&lds[base + (((grp * 2 + 1) ^ (row & 7)) << 4)]); \
      bf16x8 v;                                                               \
      v[0] = (bf16_t)f0.x; v[1] = (bf16_t)f0.y; v[2] = (bf16_t)f0.z; v[3] = (bf16_t)f0.w; \
      v[4] = (bf16_t)f1.x; v[5] = (bf16_t)f1.y; v[6] = (bf16_t)f1.z; v[7] = (bf16_t)f1.w; \
      XF[sub] = v;                                                            \
    }                                                                         \
  } while (0)

#define MFMA16(WF, XF)                                                        \
  _Pragma("unroll") for (int a = 0; a < 4; ++a)                               \
  _Pragma("unroll") for (int sub = 0; sub < 4; ++sub)                         \
    acc[a][sub] = __builtin_amdgcn_mfma_f32_16x16x32_bf16(WF[a], XF[sub], acc[a][sub], 0, 0, 0);

  bf16x8 wfA[4], wfB[4];
  // prologue: queue = [stage(0):8, wf(0):4, stage(1):8]
  stageX(0, kb0);
  LOADW(wfA, 0);
  stageX(1, kb0 + 32);

#pragma unroll 1
  for (int it = 0; it < 8; ++it) {
    int iA = it * 2;                     // even step -> buf0, wfA
    // ---- step A ----
    WAITVM(12);                          // drain stage(iA); [wf(iA):4, stage(iA+1):8] fly
    __builtin_amdgcn_sched_barrier(0);
    bf16x8 xfA[4];
    READX(xfA, 0);
    asm volatile("s_waitcnt lgkmcnt(0)" ::: "memory");
    __builtin_amdgcn_sched_barrier(0);
    LOADW(wfB, (iA + 1) * 32);           // wf(iA+1)
    if (iA + 2 < 16) stageX(0, kb0 + (iA + 2) * 32);
    MFMA16(wfA, xfA);                    // compiler waits wf(iA) via vmcnt

    // ---- step B ----
    int iB = iA + 1;                     // odd step -> buf1, wfB
    if (iB < 15) { WAITVM(12); }         // drain stage(iB)
    else         { WAITVM(4); }          // last: drain stage(15), leave wf(15)
    __builtin_amdgcn_sched_barrier(0);
    bf16x8 xfB[4];
    READX(xfB, 1);
    asm volatile("s_waitcnt lgkmcnt(0)" ::: "memory");
    __builtin_amdgcn_sched_barrier(0);
    if (iB + 1 < 16) LOADW(wfA, (iB + 1) * 32);
    if (iB + 2 < 16) stageX(1, kb0 + (iB + 2) * 32);
    MFMA16(wfB, xfB);
  }
#undef LOADW
#undef READX
#undef MFMA16

  // ---- K-half merge: waves 2,3 dump acc; waves 0,1 add; then epilogue ----
  __syncthreads();
  if (kh == 1) {
#pragma unroll
    for (int a = 0; a < 4; ++a)
#pragma unroll
      for (int sub = 0; sub < 4; ++sub)
        *(f32x4*)(&lds[nh * 16384 + lane * 256 + (a * 4 + sub) * 16]) = acc[a][sub];
  }
  __syncthreads();
  if (kh == 1) return;

#pragma unroll
  for (int a = 0; a < 4; ++a)
#pragma unroll
    for (int sub = 0; sub < 4; ++sub) {
      f32x4 o = *(const f32x4*)(&lds[nh * 16384 + lane * 256 + (a * 4 + sub) * 16]);
#pragma unroll
      for (int e = 0; e < 4; ++e) acc[a][sub][e] += o[e];
    }

  if (slice < 2) {   // Q (pre-scaled 1/32, exact in bf16) or K, row-major [t][128]
    bf16_t* dst = (slice == 0) ? q : k;
    float qs = (slice == 0) ? 0.03125f : 1.0f;
#pragma unroll
    for (int a = 0; a < 4; ++a)
#pragma unroll
      for (int sub = 0; sub < 4; ++sub) {
        bf16x4 o;
        o[0] = (bf16_t)(acc[a][sub][0] * qs); o[1] = (bf16_t)(acc[a][sub][1] * qs);
        o[2] = (bf16_t)(acc[a][sub][2] * qs); o[3] = (bf16_t)(acc[a][sub][3] * qs);
        *(bf16x4*)(dst + (size_t)(t0 + sub * 16 + lq) * 128
                   + nh * 64 + a * 16 + grp * 4) = o;
      }
  } else {           // V transposed: vT[b][d][t]
    int b = t0 >> 11;
#pragma unroll
    for (int a = 0; a < 4; ++a)
#pragma unroll
      for (int sub = 0; sub < 4; ++sub) {
        int tt = (t0 + sub * 16 + lq) & 2047;
#pragma unroll
        for (int r = 0; r < 4; ++r) {
          int d = nh * 64 + a * 16 + grp * 4 + r;
          vT[(size_t)b * 128 * 2048 + (size_t)d * 2048 + tt] = (bf16_t)acc[a][sub][r];
        }
      }
  }
}

// ---------------- flash attention v11 (unchanged: measured ~30us) -------------------
__global__ __launch_bounds__(512) void attn_kernel(const bf16_t* __restrict__ q,
                                                   const bf16_t* __restrict__ k,
                                                   const bf16_t* __restrict__ vT,
                                                   float* __restrict__ out) {
  __shared__ __align__(16) char lds[81920];

  int tid = threadIdx.x;
  int lane = tid & 63;
  int w = tid >> 6;                  // kv-split index 0..7
  int lq = lane & 15, grp = lane >> 4;
  int b = blockIdx.x & 7;            // XCD-pinned batch
  int qt = 63 - (blockIdx.x >> 3);   // heavy first; 32 q-rows
  int tq0 = qt * 32 + lq;            // qh=0 row; qh=1 row = tq0+16

  bf16x8 qf[4][2];
#pragma unroll
  for (int qh = 0; qh < 2; ++qh) {
    const bf16_t* qrow = q + ((size_t)b * 2048 + tq0 + qh * 16) * 128 + grp * 8;
#pragma unroll
    for (int ks = 0; ks < 4; ++ks) qf[ks][qh] = *(const bf16x8*)(qrow + ks * 32);
  }

  float mrun[2] = {-__builtin_inff(), -__builtin_inff()};
  float lsum[2] = {0.f, 0.f};
  f32x4 accO[8][2];
#pragma unroll
  for (int i = 0; i < 8; ++i)
#pragma unroll
    for (int qh = 0; qh < 2; ++qh) accO[i][qh] = (f32x4){0.f, 0.f, 0.f, 0.f};

  const char* kbase = (const char*)(k + (size_t)b * 2048 * 128);
  const bf16_t* vb = vT + (size_t)b * 128 * 2048;

  auto stageK = [&](int kv0) {
#pragma unroll
    for (int i = 0; i < 8; ++i) {
      int off = i * 1024 + lane * 16;
      int row = off >> 8;
      int c = (off >> 4) & 15;
      const char* src = kbase + (size_t)(kv0 + row) * 256 + ((c ^ (row & 7)) << 4);
      g2lds16(src, &lds[w * 8192 + off]);
    }
  };

  bf16x8 vf[8];
  auto loadV = [&](int kv0) {
#pragma unroll
    for (int mf = 0; mf < 8; ++mf)
      vf[mf] = *(const bf16x8*)(vb + (size_t)(mf * 16 + lq) * 2048 + kv0 + grp * 8);
  };

  int nt = qt + 1;
  int cnt = (nt - w + 7) >> 3;

  if (cnt > 0) { stageK(w * 32); loadV(w * 32); }

#pragma unroll 1
  for (int i = 0; i < cnt; ++i) {
    int kv0 = (w + 8 * i) * 32;
    bool pre = (i + 1 < cnt);

    WAITVM(8);
    __builtin_amdgcn_sched_barrier(0);

    f32x4 s[2][2];
#pragma unroll
    for (int mf = 0; mf < 2; ++mf)
#pragma unroll
      for (int qh = 0; qh < 2; ++qh) s[mf][qh] = (f32x4){0.f, 0.f, 0.f, 0.f};
#pragma unroll
    for (int ks = 0; ks < 4; ++ks)
#pragma unroll
      for (int mf = 0; mf < 2; ++mf) {
        int row = mf * 16 + lq;
        bf16x8 kf = *(const bf16x8*)(&lds[w * 8192 + row * 256
                                          + (((ks * 4 + grp) ^ (row & 7)) << 4)]);
#pragma unroll
        for (int qh = 0; qh < 2; ++qh)
          s[mf][qh] = __builtin_amdgcn_mfma_f32_16x16x32_bf16(kf, qf[ks][qh], s[mf][qh], 0, 0, 0);
      }

    asm volatile("s_waitcnt lgkmcnt(0)" ::: "memory");
    __builtin_amdgcn_sched_barrier(0);
    if (pre) stageK(kv0 + 256);

#pragma unroll
    for (int qh = 0; qh < 2; ++qh) {
      int tq = tq0 + qh * 16;
      bool hasmask = (kv0 + 31 > qt * 32 + qh * 16);
      if (hasmask) {
#pragma unroll
        for (int f = 0; f < 2; ++f)
#pragma unroll
          for (int r = 0; r < 4; ++r) {
            int kv = kv0 + f * 16 + grp * 4 + r;
            s[f][qh][r] = (kv <= tq) ? s[f][qh][r] : -__builtin_inff();
          }
      }
      float pmax = -__builtin_inff();
#pragma unroll
      for (int f = 0; f < 2; ++f)
#pragma unroll
        for (int r = 0; r < 4; ++r) pmax = fmaxf(pmax, s[f][qh][r]);
      pmax = fmaxf(pmax, __shfl_xor(pmax, 16, 64));
      pmax = fmaxf(pmax, __shfl_xor(pmax, 32, 64));

      float msub;
      if (__all(pmax <= mrun[qh])) {
        msub = mrun[qh];
      } else {
        float mnew = fmaxf(mrun[qh], pmax);
        msub = fmaxf(mnew, -3e38f);
        float corr = __expf(mrun[qh] - msub);
        lsum[qh] *= corr;
        mrun[qh] = mnew;
#pragma unroll
        for (int i2 = 0; i2 < 8; ++i2) accO[i2][qh] *= corr;
      }

      float psum = 0.f;
#pragma unroll
      for (int f = 0; f < 2; ++f) {
        bf16x4 pw;
#pragma unroll
        for (int r = 0; r < 4; ++r) {
          float pe = __expf(s[f][qh][r] - msub);
          psum += pe;
          pw[r] = (bf16_t)pe;
        }
        *(bf16x4*)(&lds[65536 + w * 2048 + qh * 1024 + ((f * 2 + (grp >> 1)) << 8)
                        + lq * 16 + ((grp & 1) << 3)]) = pw;
      }
      psum += __shfl_xor(psum, 16, 64);
      psum += __shfl_xor(psum, 32, 64);
      lsum[qh] += psum;
    }

    if (pre) { WAITVM(8); }
    else     { WAITVM(0); }
    __builtin_amdgcn_sched_barrier(0);

    bf16x8 pf0 = *(const bf16x8*)(&lds[65536 + w * 2048 + (grp << 8) + lq * 16]);
    bf16x8 pf1 = *(const bf16x8*)(&lds[65536 + w * 2048 + 1024 + (grp << 8) + lq * 16]);
#pragma unroll
    for (int mf = 0; mf < 8; ++mf) {
      accO[mf][0] = __builtin_amdgcn_mfma_f32_16x16x32_bf16(vf[mf], pf0, accO[mf][0], 0, 0, 0);
      accO[mf][1] = __builtin_amdgcn_mfma_f32_16x16x32_bf16(vf[mf], pf1, accO[mf][1], 0, 0, 0);
    }

    if (pre) loadV(kv0 + 256);
  }

  // ---- 8-way kv-split merge: 3-round LDS tree ----
#pragma unroll 1
  for (int round = 0; round < 3; ++round) {
    int stride = 4 >> round;
    __syncthreads();
    if (w >= stride && w < 2 * stride) {
      int slot = w - stride;
#pragma unroll
      for (int qh = 0; qh < 2; ++qh) {
#pragma unroll
        for (int mf = 0; mf < 8; ++mf)
          *(f32x4*)(&lds[slot * 16384 + qh * 8192 + mf * 1024 + lane * 16]) = accO[mf][qh];
        *(float*)(&lds[65536 + w * 2048 + qh * 512 + lane * 8])     = mrun[qh];
        *(float*)(&lds[65536 + w * 2048 + qh * 512 + lane * 8 + 4]) = lsum[qh];
      }
    }
    __syncthreads();
    if (w < stride) {
      int pw = w + stride;
#pragma unroll
      for (int qh = 0; qh < 2; ++qh) {
        float mB = *(const float*)(&lds[65536 + pw * 2048 + qh * 512 + lane * 8]);
        float lB = *(const float*)(&lds[65536 + pw * 2048 + qh * 512 + lane * 8 + 4]);
        float mN = fmaxf(mrun[qh], mB);
        float ms = fmaxf(mN, -3e38f);
        float cA = __expf(mrun[qh] - ms);
        float cB = __expf(mB - ms);
        lsum[qh] = lsum[qh] * cA + lB * cB;
        mrun[qh] = mN;
#pragma unroll
        for (int mf = 0; mf < 8; ++mf) {
          f32x4 OB = *(const f32x4*)(&lds[w * 16384 + qh * 8192 + mf * 1024 + lane * 16]);
#pragma unroll
          for (int e = 0; e < 4; ++e) accO[mf][qh][e] = accO[mf][qh][e] * cA + OB[e] * cB;
        }
      }
    }
  }

  if (w == 0) {
#pragma unroll
    for (int qh = 0; qh < 2; ++qh) {
      float inv = 1.0f / lsum[qh];
      float* orow = out + ((size_t)b * 2048 + tq0 + qh * 16) * 128;
#pragma unroll
      for (int mf = 0; mf < 8; ++mf) {
        f32x4 o;
#pragma unroll
        for (int e = 0; e < 4; ++e) o[e] = accO[mf][qh][e] * inv;
        *(f32x4*)(orow + mf * 16 + grp * 4) = o;
      }
    }
  }
}

extern "C" void kernel_launch(void* const* d_in, const int* in_sizes, int n_in,
                              void* d_out, int out_size, void* d_ws, size_t ws_size,
                              hipStream_t stream) {
  const float* x  = (const float*)d_in[0];
  const float* Wq = (const float*)d_in[1];
  const float* Wk = (const float*)d_in[2];
  const float* Wv = (const float*)d_in[3];
  float* out = (float*)d_out;
  char* ws = (char*)d_ws;

  bf16_t* wt = (bf16_t*)(ws + WT_OFF);
  bf16_t* qb = (bf16_t*)(ws + Q_OFF);
  bf16_t* kb = (bf16_t*)(ws + K_OFF);
  bf16_t* vT = (bf16_t*)(ws + VT_OFF);

  hipLaunchKernelGGL(wt_kernel, dim3(48), dim3(256), 0, stream, Wq, Wk, Wv, wt);
  hipLaunchKernelGGL(proj_kernel, dim3(768), dim3(256), 0, stream, x, wt, qb, kb, vT);
  hipLaunchKernelGGL(attn_kernel, dim3(512), dim3(512), 0, stream, qb, kb, vT, out);
}

// Round 17
// 78.564 us; speedup vs baseline: 1.0906x; 1.0906x over previous
//
#include <hip/hip_runtime.h>
#include <hip/hip_bf16.h>
#include <stdint.h>

typedef __bf16 bf16_t;
typedef __bf16 bf16x4 __attribute__((ext_vector_type(4)));
typedef __bf16 bf16x8 __attribute__((ext_vector_type(8)));
typedef float  f32x4  __attribute__((ext_vector_type(4)));

#define WAITVM(N) asm volatile("s_waitcnt vmcnt(" #N ")" ::: "memory")

// ---- workspace layout (bytes) ----
static constexpr size_t WT_OFF = 0;                    // Wt bf16 [384][1024] = 768 KB
static constexpr size_t Q_OFF  = (size_t)1 << 20;      // q bf16 (pre-scaled 1/32) 4 MB
static constexpr size_t K_OFF  = Q_OFF + ((size_t)4 << 20);
static constexpr size_t VT_OFF = K_OFF + ((size_t)4 << 20);  // vT bf16 [8][128][2048] = 4 MB

__device__ __forceinline__ void g2lds16(const void* g, void* l) {
  __builtin_amdgcn_global_load_lds(
      (__attribute__((address_space(1))) void*)(g),
      (__attribute__((address_space(3))) void*)(l), 16, 0, 0);
}

// ---------------- W transpose: W[1024][128] fp32 -> Wt[384][1024] bf16 ----------------
__global__ __launch_bounds__(256) void wt_kernel(const float* __restrict__ Wq,
                                                 const float* __restrict__ Wk,
                                                 const float* __restrict__ Wv,
                                                 bf16_t* __restrict__ wt) {
  __shared__ float tile[64][129];
  int wi = blockIdx.x >> 4;
  int ct = blockIdx.x & 15;
  const float* W = (wi == 0) ? Wq : ((wi == 1) ? Wk : Wv);
  int c0 = ct * 64;
  int tid = threadIdx.x;
  for (int i = 0; i < 32; ++i) {
    int idx = i * 256 + tid;
    int c = idx >> 7, n = idx & 127;
    tile[c][n] = W[(size_t)(c0 + c) * 128 + n];
  }
  __syncthreads();
  for (int i = 0; i < 32; ++i) {
    int idx = i * 256 + tid;
    int n = idx >> 6, c = idx & 63;
    wt[(size_t)(wi * 128 + n) * 1024 + c0 + c] = (bf16_t)tile[c][n];
  }
}

// ---------------- fused QKV projection v6 (measured 44.6us, session best) -----------
// Grid 768 = 3 slices x 256 t-tiles(64), XCD-chunked. Block 128 thr = 2 waves.
// Per BK=64 step: 8 wf loads (L2) + stage next x-tile (8 g2lds) + WAITVM(16)
// (stage(ks) drained; wf(ks)+stage(ks+1) in flight) + barrier + 16 ds_read + cvt
// + 32 MFMA + barrier. Seven rewrites (v7-v12) all regressed; this is the keeper.
__global__ __launch_bounds__(128) void proj_kernel(const float* __restrict__ x,
                                                   const bf16_t* __restrict__ wt,
                                                   bf16_t* __restrict__ q,
                                                   bf16_t* __restrict__ k,
                                                   bf16_t* __restrict__ vT) {
  __shared__ __align__(16) char Blds[2][16384];  // x tile [64 t][64 k] f32, 16B-chunk XOR swz

  int wgid = (blockIdx.x & 7) * 96 + (blockIdx.x >> 3);
  int t_tile = wgid / 3;
  int slice = wgid % 3;          // 0=Q, 1=K, 2=V
  int n0 = slice * 128;
  int t0 = t_tile * 64;

  int tid = threadIdx.x;
  int lane = tid & 63;
  int wave = tid >> 6;           // n-half
  int lq = lane & 15, grp = lane >> 4;

  const char* xb = (const char*)x;   // global row stride 4096 B

  f32x4 acc[4][4];
#pragma unroll
  for (int a = 0; a < 4; ++a)
#pragma unroll
    for (int s = 0; s < 4; ++s) acc[a][s] = (f32x4){0.f, 0.f, 0.f, 0.f};

  const bf16_t* wbase = wt + (size_t)(n0 + wave * 64 + lq) * 1024 + grp * 8;

  auto stageB = [&](int bi, int k0) {
#pragma unroll
    for (int i = 0; i < 8; ++i) {
      int off = i * 2048 + tid * 16;
      int row = off >> 8;
      int c = (off >> 4) & 15;
      const char* src = xb + (size_t)(t0 + row) * 4096 + (size_t)k0 * 4
                        + ((c ^ (row & 15)) << 4);
      g2lds16(src, &Blds[bi][off]);
    }
  };

  stageB(0, 0);

  for (int ks = 0; ks < 16; ++ks) {
    int cur = ks & 1;
    int k0 = ks * 64;

    bf16x8 wf[4][2];
#pragma unroll
    for (int kh = 0; kh < 2; ++kh)
#pragma unroll
      for (int a = 0; a < 4; ++a)
        wf[a][kh] = *(const bf16x8*)(wbase + (size_t)(a * 16) * 1024 + k0 + kh * 32);

    if (ks < 15) {
      stageB(cur ^ 1, (ks + 1) * 64);
      WAITVM(16);              // drains stage(ks); wf(ks)+stage(ks+1) may stay in flight
    } else {
      WAITVM(8);
    }
    __builtin_amdgcn_s_barrier();
    __builtin_amdgcn_sched_barrier(0);

    bf16x8 xf[4][2];
#pragma unroll
    for (int sub = 0; sub < 4; ++sub) {
      int row = sub * 16 + lq;
#pragma unroll
      for (int kh = 0; kh < 2; ++kh) {
        int c0 = kh * 8 + grp * 2;
        float4 f0 = *(const float4*)(&Blds[cur][row * 256 + (((c0)     ^ (row & 15)) << 4)]);
        float4 f1 = *(const float4*)(&Blds[cur][row * 256 + (((c0 + 1) ^ (row & 15)) << 4)]);
        bf16x8 v;
        v[0] = (bf16_t)f0.x; v[1] = (bf16_t)f0.y; v[2] = (bf16_t)f0.z; v[3] = (bf16_t)f0.w;
        v[4] = (bf16_t)f1.x; v[5] = (bf16_t)f1.y; v[6] = (bf16_t)f1.z; v[7] = (bf16_t)f1.w;
        xf[sub][kh] = v;
      }
    }

#pragma unroll
    for (int kh = 0; kh < 2; ++kh)
#pragma unroll
      for (int a = 0; a < 4; ++a)
#pragma unroll
        for (int sub = 0; sub < 4; ++sub)
          acc[a][sub] = __builtin_amdgcn_mfma_f32_16x16x32_bf16(wf[a][kh], xf[sub][kh],
                                                                acc[a][sub], 0, 0, 0);
    __builtin_amdgcn_s_barrier();
  }

  if (slice < 2) {   // Q (pre-scaled 1/32, exact in bf16) or K, row-major [t][128]
    bf16_t* dst = (slice == 0) ? q : k;
    float qs = (slice == 0) ? 0.03125f : 1.0f;
#pragma unroll
    for (int a = 0; a < 4; ++a)
#pragma unroll
      for (int sub = 0; sub < 4; ++sub) {
        bf16x4 o;
        o[0] = (bf16_t)(acc[a][sub][0] * qs); o[1] = (bf16_t)(acc[a][sub][1] * qs);
        o[2] = (bf16_t)(acc[a][sub][2] * qs); o[3] = (bf16_t)(acc[a][sub][3] * qs);
        *(bf16x4*)(dst + (size_t)(t0 + sub * 16 + lq) * 128 + wave * 64 + a * 16 + grp * 4) = o;
      }
  } else {           // V transposed: vT[b][d][t]
    int b = t0 >> 11;
#pragma unroll
    for (int a = 0; a < 4; ++a)
#pragma unroll
      for (int sub = 0; sub < 4; ++sub) {
        int tt = (t0 + sub * 16 + lq) & 2047;
#pragma unroll
        for (int r = 0; r < 4; ++r) {
          int d = wave * 64 + a * 16 + grp * 4 + r;
          vT[(size_t)b * 128 * 2048 + (size_t)d * 2048 + tt] = (bf16_t)acc[a][sub][r];
        }
      }
  }
}

// ---------------- flash attention v11 (measured ~30us, session best) ----------------
// 512 blocks = 8 b (XCD-pinned) x 64 q-tiles(32 rows), heavy-first; 8 waves/block.
// Each wave: TWO 16-row q-groups sharing one K-LDS tile + V-regs (2x MFMA/byte);
// per-wave pipeline, counted vmcnt, no loop barriers; 8-way kv-split, 3-round merge.
__global__ __launch_bounds__(512) void attn_kernel(const bf16_t* __restrict__ q,
                                                   const bf16_t* __restrict__ k,
                                                   const bf16_t* __restrict__ vT,
                                                   float* __restrict__ out) {
  __shared__ __align__(16) char lds[81920];

  int tid = threadIdx.x;
  int lane = tid & 63;
  int w = tid >> 6;                  // kv-split index 0..7
  int lq = lane & 15, grp = lane >> 4;
  int b = blockIdx.x & 7;            // XCD-pinned batch
  int qt = 63 - (blockIdx.x >> 3);   // heavy first; 32 q-rows
  int tq0 = qt * 32 + lq;            // qh=0 row; qh=1 row = tq0+16

  bf16x8 qf[4][2];
#pragma unroll
  for (int qh = 0; qh < 2; ++qh) {
    const bf16_t* qrow = q + ((size_t)b * 2048 + tq0 + qh * 16) * 128 + grp * 8;
#pragma unroll
    for (int ks = 0; ks < 4; ++ks) qf[ks][qh] = *(const bf16x8*)(qrow + ks * 32);
  }

  float mrun[2] = {-__builtin_inff(), -__builtin_inff()};
  float lsum[2] = {0.f, 0.f};
  f32x4 accO[8][2];
#pragma unroll
  for (int i = 0; i < 8; ++i)
#pragma unroll
    for (int qh = 0; qh < 2; ++qh) accO[i][qh] = (f32x4){0.f, 0.f, 0.f, 0.f};

  const char* kbase = (const char*)(k + (size_t)b * 2048 * 128);
  const bf16_t* vb = vT + (size_t)b * 128 * 2048;

  auto stageK = [&](int kv0) {
#pragma unroll
    for (int i = 0; i < 8; ++i) {
      int off = i * 1024 + lane * 16;
      int row = off >> 8;
      int c = (off >> 4) & 15;
      const char* src = kbase + (size_t)(kv0 + row) * 256 + ((c ^ (row & 7)) << 4);
      g2lds16(src, &lds[w * 8192 + off]);
    }
  };

  bf16x8 vf[8];
  auto loadV = [&](int kv0) {
#pragma unroll
    for (int mf = 0; mf < 8; ++mf)
      vf[mf] = *(const bf16x8*)(vb + (size_t)(mf * 16 + lq) * 2048 + kv0 + grp * 8);
  };

  int nt = qt + 1;
  int cnt = (nt - w + 7) >> 3;

  if (cnt > 0) { stageK(w * 32); loadV(w * 32); }

#pragma unroll 1
  for (int i = 0; i < cnt; ++i) {
    int kv0 = (w + 8 * i) * 32;
    bool pre = (i + 1 < cnt);

    WAITVM(8);
    __builtin_amdgcn_sched_barrier(0);

    f32x4 s[2][2];
#pragma unroll
    for (int mf = 0; mf < 2; ++mf)
#pragma unroll
      for (int qh = 0; qh < 2; ++qh) s[mf][qh] = (f32x4){0.f, 0.f, 0.f, 0.f};
#pragma unroll
    for (int ks = 0; ks < 4; ++ks)
#pragma unroll
      for (int mf = 0; mf < 2; ++mf) {
        int row = mf * 16 + lq;
        bf16x8 kf = *(const bf16x8*)(&lds[w * 8192 + row * 256
                                          + (((ks * 4 + grp) ^ (row & 7)) << 4)]);
#pragma unroll
        for (int qh = 0; qh < 2; ++qh)
          s[mf][qh] = __builtin_amdgcn_mfma_f32_16x16x32_bf16(kf, qf[ks][qh], s[mf][qh], 0, 0, 0);
      }

    asm volatile("s_waitcnt lgkmcnt(0)" ::: "memory");
    __builtin_amdgcn_sched_barrier(0);
    if (pre) stageK(kv0 + 256);

#pragma unroll
    for (int qh = 0; qh < 2; ++qh) {
      int tq = tq0 + qh * 16;
      bool hasmask = (kv0 + 31 > qt * 32 + qh * 16);
      if (hasmask) {
#pragma unroll
        for (int f = 0; f < 2; ++f)
#pragma unroll
          for (int r = 0; r < 4; ++r) {
            int kv = kv0 + f * 16 + grp * 4 + r;
            s[f][qh][r] = (kv <= tq) ? s[f][qh][r] : -__builtin_inff();
          }
      }
      float pmax = -__builtin_inff();
#pragma unroll
      for (int f = 0; f < 2; ++f)
#pragma unroll
        for (int r = 0; r < 4; ++r) pmax = fmaxf(pmax, s[f][qh][r]);
      pmax = fmaxf(pmax, __shfl_xor(pmax, 16, 64));
      pmax = fmaxf(pmax, __shfl_xor(pmax, 32, 64));

      float msub;
      if (__all(pmax <= mrun[qh])) {
        msub = mrun[qh];
      } else {
        float mnew = fmaxf(mrun[qh], pmax);
        msub = fmaxf(mnew, -3e38f);
        float corr = __expf(mrun[qh] - msub);
        lsum[qh] *= corr;
        mrun[qh] = mnew;
#pragma unroll
        for (int i2 = 0; i2 < 8; ++i2) accO[i2][qh] *= corr;
      }

      float psum = 0.f;
#pragma unroll
      for (int f = 0; f < 2; ++f) {
        bf16x4 pw;
#pragma unroll
        for (int r = 0; r < 4; ++r) {
          float pe = __expf(s[f][qh][r] - msub);
          psum += pe;
          pw[r] = (bf16_t)pe;
        }
        *(bf16x4*)(&lds[65536 + w * 2048 + qh * 1024 + ((f * 2 + (grp >> 1)) << 8)
                        + lq * 16 + ((grp & 1) << 3)]) = pw;
      }
      psum += __shfl_xor(psum, 16, 64);
      psum += __shfl_xor(psum, 32, 64);
      lsum[qh] += psum;
    }

    if (pre) { WAITVM(8); }
    else     { WAITVM(0); }
    __builtin_amdgcn_sched_barrier(0);

    bf16x8 pf0 = *(const bf16x8*)(&lds[65536 + w * 2048 + (grp << 8) + lq * 16]);
    bf16x8 pf1 = *(const bf16x8*)(&lds[65536 + w * 2048 + 1024 + (grp << 8) + lq * 16]);
#pragma unroll
    for (int mf = 0; mf < 8; ++mf) {
      accO[mf][0] = __builtin_amdgcn_mfma_f32_16x16x32_bf16(vf[mf], pf0, accO[mf][0], 0, 0, 0);
      accO[mf][1] = __builtin_amdgcn_mfma_f32_16x16x32_bf16(vf[mf], pf1, accO[mf][1], 0, 0, 0);
    }

    if (pre) loadV(kv0 + 256);
  }

  // ---- 8-way kv-split merge: 3-round LDS tree ----
#pragma unroll 1
  for (int round = 0; round < 3; ++round) {
    int stride = 4 >> round;
    __syncthreads();
    if (w >= stride && w < 2 * stride) {
      int slot = w - stride;
#pragma unroll
      for (int qh = 0; qh < 2; ++qh) {
#pragma unroll
        for (int mf = 0; mf < 8; ++mf)
          *(f32x4*)(&lds[slot * 16384 + qh * 8192 + mf * 1024 + lane * 16]) = accO[mf][qh];
        *(float*)(&lds[65536 + w * 2048 + qh * 512 + lane * 8])     = mrun[qh];
        *(float*)(&lds[65536 + w * 2048 + qh * 512 + lane * 8 + 4]) = lsum[qh];
      }
    }
    __syncthreads();
    if (w < stride) {
      int pw = w + stride;
#pragma unroll
      for (int qh = 0; qh < 2; ++qh) {
        float mB = *(const float*)(&lds[65536 + pw * 2048 + qh * 512 + lane * 8]);
        float lB = *(const float*)(&lds[65536 + pw * 2048 + qh * 512 + lane * 8 + 4]);
        float mN = fmaxf(mrun[qh], mB);
        float ms = fmaxf(mN, -3e38f);
        float cA = __expf(mrun[qh] - ms);
        float cB = __expf(mB - ms);
        lsum[qh] = lsum[qh] * cA + lB * cB;
        mrun[qh] = mN;
#pragma unroll
        for (int mf = 0; mf < 8; ++mf) {
          f32x4 OB = *(const f32x4*)(&lds[w * 16384 + qh * 8192 + mf * 1024 + lane * 16]);
#pragma unroll
          for (int e = 0; e < 4; ++e) accO[mf][qh][e] = accO[mf][qh][e] * cA + OB[e] * cB;
        }
      }
    }
  }

  if (w == 0) {
#pragma unroll
    for (int qh = 0; qh < 2; ++qh) {
      float inv = 1.0f / lsum[qh];
      float* orow = out + ((size_t)b * 2048 + tq0 + qh * 16) * 128;
#pragma unroll
      for (int mf = 0; mf < 8; ++mf) {
        f32x4 o;
#pragma unroll
        for (int e = 0; e < 4; ++e) o[e] = accO[mf][qh][e] * inv;
        *(f32x4*)(orow + mf * 16 + grp * 4) = o;
      }
    }
  }
}

extern "C" void kernel_launch(void* const* d_in, const int* in_sizes, int n_in,
                              void* d_out, int out_size, void* d_ws, size_t ws_size,
                              hipStream_t stream) {
  const float* x  = (const float*)d_in[0];
  const float* Wq = (const float*)d_in[1];
  const float* Wk = (const float*)d_in[2];
  const float* Wv = (const float*)d_in[3];
  float* out = (float*)d_out;
  char* ws = (char*)d_ws;

  bf16_t* wt = (bf16_t*)(ws + WT_OFF);
  bf16_t* qb = (bf16_t*)(ws + Q_OFF);
  bf16_t* kb = (bf16_t*)(ws + K_OFF);
  bf16_t* vT = (bf16_t*)(ws + VT_OFF);

  hipLaunchKernelGGL(wt_kernel, dim3(48), dim3(256), 0, stream, Wq, Wk, Wv, wt);
  hipLaunchKernelGGL(proj_kernel, dim3(768), dim3(128), 0, stream, x, wt, qb, kb, vT);
  hipLaunchKernelGGL(attn_kernel, dim3(512), dim3(512), 0, stream, qb, kb, vT, out);
}